// Round 1
// 284.395 us; speedup vs baseline: 1.0814x; 1.0814x over previous
//
#include <hip/hip_runtime.h>
#include <hip/hip_bf16.h>
#include <math.h>

// SpatialAttention B=8, C_IN=256 (d_v), C_OUT=128 (d_qk), N=4096.
// Round 8: flash restructured to ONE barrier per k-tile (V triple-buffered,
// P double-buffered, K double-buffered) -> 128 barrier drains instead of 256,
// V DMA gets a full halfstep of flight. P packing rewritten: DPP quad_perm
// lane^1 exchange (VALU pipe, replaces ds_bpermute) + v_cvt_pk_bf16_f32
// (1 instr per packed pair, replaces ~11 VALU manual RNE). s_setprio(1)
// around both MFMA clusters (T5).
//   cvt_w : Wq*log2e, Wk -> fp16; bqs = bq*log2e          (unchanged)
//   proj3 : native [c][n] fp32 -> LDS transpose -> MFMA   (unchanged)
//   flash : S mfma f16, P = 2^(S') unnormalized bf16, PV mfma bf16,
//           divide-by-l epilogue.

#define B_   8
#define CIN  256
#define COUT 128
#define NN   4096

typedef _Float16 half8  __attribute__((ext_vector_type(8)));
typedef short    short8 __attribute__((ext_vector_type(8)));
typedef float    f32x4  __attribute__((ext_vector_type(4)));

#define LOG2E 1.44269504088896340736f

__device__ __forceinline__ unsigned short f2bf(float f) {
    union { float f; unsigned u; } v; v.f = f;
    return (unsigned short)((v.u + 0x7FFFu + ((v.u >> 16) & 1u)) >> 16);
}
__device__ __forceinline__ unsigned short f2h(float f) {
    union { _Float16 h; unsigned short u; } v; v.h = (_Float16)f;
    return v.u;
}
// packed f32x2 -> bf16x2 in one VALU op (no builtin on gfx950; inline asm)
__device__ __forceinline__ unsigned int cvt_pk_bf16(float lo, float hi) {
    unsigned int r;
    asm("v_cvt_pk_bf16_f32 %0, %1, %2" : "=v"(r) : "v"(lo), "v"(hi));
    return r;
}
// lane^1 exchange on the VALU pipe: DPP quad_perm [1,0,3,2] (ctrl 0xB1)
__device__ __forceinline__ float dpp_xor1(float x) {
    union { float f; int i; } u; u.f = x;
    u.i = __builtin_amdgcn_mov_dpp(u.i, 0xB1, 0xF, 0xF, true);
    return u.f;
}
// async 16B global->LDS; LDS dest = wave-uniform base + lane*16
__device__ __forceinline__ void dma16(void* lds, const void* g) {
    __builtin_amdgcn_global_load_lds(
        (const __attribute__((address_space(1))) unsigned int*)g,
        (__attribute__((address_space(3))) unsigned int*)lds,
        16, 0, 0);
}

// ---- weights: Whq = Wq*log2e (fp16), Whk = Wk (fp16); bqs = bq*log2e ----
__global__ __launch_bounds__(256) void cvt_w(const float* __restrict__ Wq,
                                             const float* __restrict__ Wk,
                                             const float* __restrict__ bq,
                                             _Float16* __restrict__ Whq,
                                             _Float16* __restrict__ Whk,
                                             float* __restrict__ bqs) {
    const int bx = blockIdx.x, t = threadIdx.x;
    const int isK = (bx >= 32);
    const float* src = isK ? Wk : Wq;
    _Float16* dst = isK ? Whk : Whq;
    const float scale = isK ? 1.0f : LOG2E;
    const int idx = (bx & 31) * 256 + t;
    float4 v = ((const float4*)src)[idx];
    unsigned long long pk = (unsigned long long)f2h(v.x * scale)
                          | ((unsigned long long)f2h(v.y * scale) << 16)
                          | ((unsigned long long)f2h(v.z * scale) << 32)
                          | ((unsigned long long)f2h(v.w * scale) << 48);
    ((unsigned long long*)dst)[idx] = pk;
    if (bx == 0 && t < COUT) bqs[t] = bq[t] * LOG2E;
}

// ---- projection; Q pass -> outN, K pass -> outT (swizzled tiled) + Vb ----
__global__ __launch_bounds__(256) void proj3(const float* __restrict__ X,     // [B][CIN][NN] fp32
                                             const _Float16* __restrict__ Wh, // [COUT][CIN] fp16
                                             const float* __restrict__ bias,  // [COUT] fp32
                                             _Float16* __restrict__ outN,     // [B][NN][COUT] or null
                                             _Float16* __restrict__ outT,     // tiled K or null
                                             unsigned short* __restrict__ Vb) // [B][CIN][NN] bf16 / null
{
    __shared__ __align__(16) unsigned short T[64 * 264];
    const int bx = blockIdx.x, b = bx >> 6, n0 = (bx & 63) << 6;
    const int t  = threadIdx.x;
    const int cr = t >> 2;
    const int nch = (t & 3) << 4;

#pragma unroll
    for (int it = 0; it < 4; ++it) {
        const int c = it * 64 + cr;
        const float* src = X + ((size_t)(b * CIN + c) * NN + n0 + nch);
        float v[16];
#pragma unroll
        for (int k = 0; k < 4; ++k) {
            float4 f = *(const float4*)(src + k * 4);
            v[k*4] = f.x; v[k*4+1] = f.y; v[k*4+2] = f.z; v[k*4+3] = f.w;
        }
#pragma unroll
        for (int j = 0; j < 16; ++j) T[(nch + j) * 264 + c] = f2h(v[j]);
        if (Vb) {
            unsigned short o[16];
#pragma unroll
            for (int j = 0; j < 16; ++j) o[j] = f2bf(v[j]);
            unsigned short* dst = Vb + (size_t)(b * CIN + c) * NN + n0 + nch;
            *(int4*)dst = *(int4*)o;
            *(int4*)(dst + 8) = *(int4*)(o + 8);
        }
    }
    __syncthreads();

    const int w = t >> 6, lane = t & 63, l15 = lane & 15, quad = lane >> 4, q8 = quad * 8;
    half8 a[8];
#pragma unroll
    for (int s = 0; s < 8; ++s)
        a[s] = *(const half8*)&T[(w * 16 + l15) * 264 + s * 32 + q8];
    f32x4 D[8];
#pragma unroll
    for (int og = 0; og < 8; ++og) D[og] = (f32x4){0.f, 0.f, 0.f, 0.f};
#pragma unroll
    for (int s = 0; s < 8; ++s) {
        const _Float16* wp = Wh + (size_t)l15 * CIN + s * 32 + q8;
#pragma unroll
        for (int og = 0; og < 8; ++og) {
            half8 wf = *(const half8*)(wp + og * 16 * CIN);
            D[og] = __builtin_amdgcn_mfma_f32_16x16x32_f16(a[s], wf, D[og], 0, 0, 0);
        }
    }
    const int nrow = n0 + w * 16 + quad * 4;
    if (outT) {
        // swizzled tiled K layout: tile = n>>5 (8KB contiguous), within:
        // halfs addr = (c*32 + ((m + 4*(c&7)) & 31))*8 + (o&7), c = o>>3, m = n&31
#pragma unroll
        for (int og = 0; og < 8; ++og) {
            const int o = og * 16 + l15;
            const float bo = bias[o];
            const int c = o >> 3, j = o & 7;
            const int sw = (c & 7) << 2;
#pragma unroll
            for (int r2 = 0; r2 < 4; ++r2) {
                const int n = nrow + r2;
                const int tile = n >> 5, m = n & 31;
                const size_t pos = ((size_t)(b * 128 + tile) * 512
                                    + c * 32 + ((m + sw) & 31)) * 8 + j;
                outT[pos] = (_Float16)(D[og][r2] + bo);
            }
        }
    } else {
#pragma unroll
        for (int og = 0; og < 8; ++og) {
            const int o = og * 16 + l15;
            const float bo = bias[o];
            _Float16* op = outN + ((size_t)(b * NN + nrow) * COUT + o);
#pragma unroll
            for (int r2 = 0; r2 < 4; ++r2)
                op[(size_t)r2 * COUT] = (_Float16)(D[og][r2] + bo);
        }
    }
}

// ---- flash attention: single barrier per k-tile, c-split PV ----
// Q fp16 [b][4096][128] (pre-scaled by log2e); Ktt fp16 swizzled-tiled;
// V bf16 [b][256][4096]; out fp32 [b][256][4096]
// Buffers: K double (8KB x2), V triple (16KB x3), P double (5KB x2) = 74.25KB
__global__ __launch_bounds__(256, 2) void flash_kernel(const _Float16* __restrict__ Q,
                                                       const _Float16* __restrict__ Ktt,
                                                       const unsigned short* __restrict__ V,
                                                       float* __restrict__ out) {
    __shared__ __align__(16) _Float16       K0sh[32 * 128];
    __shared__ __align__(16) _Float16       K1sh[32 * 128];
    __shared__ __align__(16) unsigned short V0sh[256 * 32];
    __shared__ __align__(16) unsigned short V1sh[256 * 32];
    __shared__ __align__(16) unsigned short V2sh[256 * 32];
    __shared__ __align__(16) unsigned short P0sh[64 * 40];
    __shared__ __align__(16) unsigned short P1sh[64 * 40];
    __shared__ __align__(16) float          Lsh[64];

    const int bx   = blockIdx.x;          // 512 = B * 64 q-tiles
    const int b    = bx >> 6;
    const int q0   = (bx & 63) << 6;
    const int t    = threadIdx.x;
    const int w    = t >> 6;
    const int lane = t & 63;
    const int l15  = lane & 15;
    const int quad = lane >> 4;
    const int q8   = quad * 8;

    const _Float16* Qg = Q + (size_t)b * NN * COUT;
    const _Float16* Kb = Ktt + (size_t)b * 128 * 4096;   // 128 tiles x 4096 halfs
    const unsigned short* Vg = V + (size_t)b * CIN * NN;

    // Q fragments: wave w owns S rows q0+w*16 .. +15, resident all kernel
    half8 Qf[4];
    {
        const _Float16* qr = Qg + (size_t)(q0 + w * 16 + l15) * COUT;
#pragma unroll
        for (int s = 0; s < 4; ++s)
            Qf[s] = *(const half8*)(qr + s * 32 + q8);
    }

    f32x4 O[16];   // O[ni*4+cj]: n-block ni (16 n), c = w*64 + cj*16 + l15
#pragma unroll
    for (int i = 0; i < 16; ++i) O[i] = (f32x4){0.f, 0.f, 0.f, 0.f};
    float lsum[4] = {0.f, 0.f, 0.f, 0.f};

    // V DMA source remap (layout: chunk(c,mq) at position c*4 + ((mq+(c>>1))&3))
    const int vmq   = ((lane & 3) - ((lane >> 3) & 3)) & 3;   // mq this lane fetches
    const int vcrow = lane >> 2;                              // row-within-16 group
    // V read swizzle (hoisted): slot = (quad + (l15>>1)) & 3
    const int vslot = (quad + (l15 >> 1)) & 3;

    auto issueK = [&](int kt, _Float16* Kd) {
        const _Float16* gk = Kb + (size_t)kt * 4096;
        dma16(Kd + (w * 2 + 0) * 512, gk + (w * 2 + 0) * 512 + lane * 8);
        dma16(Kd + (w * 2 + 1) * 512, gk + (w * 2 + 1) * 512 + lane * 8);
    };
    auto issueV = [&](int kt, unsigned short* Vd) {
        const int k0 = kt << 5;
#pragma unroll
        for (int i = 0; i < 4; ++i) {
            const int cc = (w * 4 + i) * 16 + vcrow;
            dma16(Vd + (w * 4 + i) * 512,
                  Vg + (size_t)cc * NN + k0 + vmq * 8);
        }
    };

    // one k-tile (32 keys), single barrier:
    //   issueK(kt+1)->Kn ; S from Kc ; exp ; pack -> Pc ; BARRIER
    //   (drains K(kt+1) + V(kt+1)) ; issueV(kt+2)->Vn2 ; PV from Pc,Va
    auto halfstep = [&](int kt, const _Float16* Kc, _Float16* Kn,
                        const unsigned short* Va, unsigned short* Vn2,
                        unsigned short* Pc) {
        if (kt + 1 < 128) issueK(kt + 1, Kn);     // flies during S; drains at barrier

        // ---- S' = (Q*log2e) K^T : wave's 16 n rows x 32 m ----
        f32x4 S0 = {0.f, 0.f, 0.f, 0.f}, S1 = {0.f, 0.f, 0.f, 0.f};
        __builtin_amdgcn_s_setprio(1);
#pragma unroll
        for (int s = 0; s < 4; ++s) {
            const int kc = 4 * s + quad;          // K k-chunk (8 o's)
            const int sw = (kc & 7) << 2;
            const int x0 = (l15 + sw) & 31;
            half8 kf0 = *(const half8*)(Kc + (kc * 32 + x0) * 8);
            half8 kf1 = *(const half8*)(Kc + (kc * 32 + (x0 ^ 16)) * 8);
            S0 = __builtin_amdgcn_mfma_f32_16x16x32_f16(Qf[s], kf0, S0, 0, 0, 0);
            S1 = __builtin_amdgcn_mfma_f32_16x16x32_f16(Qf[s], kf1, S1, 0, 0, 0);
        }
        __builtin_amdgcn_s_setprio(0);

        // ---- P = 2^S' (unnormalized e^S); accumulate l ----
        f32x4 E0, E1;
#pragma unroll
        for (int r = 0; r < 4; ++r) {
            E0[r] = exp2f(S0[r]);
            E1[r] = exp2f(S1[r]);
            lsum[r] += E0[r] + E1[r];
        }
        // lane^1 exchange via DPP (VALU), pack via v_cvt_pk_bf16_f32
        {
            f32x4 P0, P1;
#pragma unroll
            for (int r = 0; r < 4; ++r) { P0[r] = dpp_xor1(E0[r]); P1[r] = dpp_xor1(E1[r]); }
            const int odd = l15 & 1;
            unsigned short* wp0 = Pc + w * 640
                                + (((quad << 2) + (odd << 1)) * 40) + (l15 & ~1);
            unsigned int pk0 = cvt_pk_bf16(odd ? P0[2] : E0[0], odd ? E0[2] : P0[0]);
            unsigned int pk1 = cvt_pk_bf16(odd ? P0[3] : E0[1], odd ? E0[3] : P0[1]);
            unsigned int pk2 = cvt_pk_bf16(odd ? P1[2] : E1[0], odd ? E1[2] : P1[0]);
            unsigned int pk3 = cvt_pk_bf16(odd ? P1[3] : E1[1], odd ? E1[3] : P1[1]);
            *(unsigned int*)&wp0[0]  = pk0;
            *(unsigned int*)&wp0[40] = pk1;
            *(unsigned int*)&wp0[16] = pk2;
            *(unsigned int*)&wp0[56] = pk3;
        }

        __syncthreads();   // P visible; K(kt+1) and V(kt+1) DMA drained

        if (kt + 2 < 128) issueV(kt + 2, Vn2);    // full halfstep of flight

        // ---- PV: wave owns c-slice w*64..+63, all 64 n ----
        {
            short8 pf[4];
#pragma unroll
            for (int ni = 0; ni < 4; ++ni)
                pf[ni] = *(const short8*)(Pc + (ni * 16 + l15) * 40 + q8);
            const unsigned short* vb = Va + (w * 64 + l15) * 32 + vslot * 8;
            __builtin_amdgcn_s_setprio(1);
#pragma unroll
            for (int cj = 0; cj < 4; ++cj) {
                short8 vf = *(const short8*)(vb + cj * 512);   // +16 c rows
#pragma unroll
                for (int ni = 0; ni < 4; ++ni)
                    O[ni * 4 + cj] = __builtin_amdgcn_mfma_f32_16x16x32_bf16(pf[ni], vf, O[ni * 4 + cj], 0, 0, 0);
            }
            __builtin_amdgcn_s_setprio(0);
        }
        // no trailing barrier: next tile's P goes to the other P buffer,
        // next K DMA targets the buffer whose readers finished pre-barrier,
        // V DMA two tiles ahead targets the slot last read before the barrier.
    };

    issueK(0, K0sh);
    issueV(0, V0sh);
    issueV(1, V1sh);
    __syncthreads();

    _Float16*       Kc = K0sh; _Float16*       Kn = K1sh;
    unsigned short* Va = V0sh; unsigned short* Vm = V1sh; unsigned short* Vn2 = V2sh;
    unsigned short* Pc = P0sh; unsigned short* Pn = P1sh;
#pragma unroll 1
    for (int kt = 0; kt < 128; ++kt) {
        halfstep(kt, Kc, Kn, Va, Vn2, Pc);
        _Float16* tk = Kc; Kc = Kn; Kn = tk;
        unsigned short* tv = Va; Va = Vm; Vm = Vn2; Vn2 = tv;
        unsigned short* tp = Pc; Pc = Pn; Pn = tp;
    }

    // ---- epilogue: row sums -> Lsh, divide, vectorized store ----
#pragma unroll
    for (int r = 0; r < 4; ++r) {
        float s = lsum[r];
        s += __shfl_xor(s, 1);
        s += __shfl_xor(s, 2);
        s += __shfl_xor(s, 4);
        s += __shfl_xor(s, 8);
        if (l15 == 0) Lsh[w * 16 + (quad << 2) + r] = s;
    }
    __syncthreads();
    float* ob = out + (size_t)b * CIN * NN + q0;
#pragma unroll
    for (int ni = 0; ni < 4; ++ni) {
        const f32x4 lv = *(const f32x4*)&Lsh[ni * 16 + (quad << 2)];
        f32x4 linv;
#pragma unroll
        for (int r = 0; r < 4; ++r) linv[r] = 1.0f / lv[r];
        const int nb = ni * 16 + (quad << 2);
#pragma unroll
        for (int cj = 0; cj < 4; ++cj) {
            const int c = w * 64 + cj * 16 + l15;
            f32x4 val = O[ni * 4 + cj];
#pragma unroll
            for (int r = 0; r < 4; ++r) val[r] *= linv[r];
            *(f32x4*)(ob + (size_t)c * NN + nb) = val;
        }
    }
}

extern "C" void kernel_launch(void* const* d_in, const int* in_sizes, int n_in,
                              void* d_out, int out_size, void* d_ws, size_t ws_size,
                              hipStream_t stream) {
    const float* p  = (const float*)d_in[0];
    const float* bv = (const float*)d_in[1];
    const float* Wq = (const float*)d_in[2];
    const float* bq = (const float*)d_in[3];
    const float* Wk = (const float*)d_in[4];
    const float* bk = (const float*)d_in[5];
    float* outp = (float*)d_out;

    char* ws = (char*)d_ws;
    const size_t szQ = (size_t)B_ * NN * COUT * 2;   // 8.4 MB (fp16)
    const size_t szV = (size_t)B_ * NN * CIN * 2;    // 16.8 MB (bf16)
    const size_t szW = (size_t)COUT * CIN * 2;       // 64 KB
    _Float16*       Qh  = (_Float16*)ws;
    _Float16*       Ktt = (_Float16*)(ws + szQ);
    unsigned short* Vb  = (unsigned short*)(ws + 2 * szQ);
    _Float16*       Whq = (_Float16*)(ws + 2 * szQ + szV);
    _Float16*       Whk = (_Float16*)(ws + 2 * szQ + szV + szW);
    float*          bqs = (float*)(ws + 2 * szQ + szV + 2 * szW);

    cvt_w<<<64, 256, 0, stream>>>(Wq, Wk, bq, Whq, Whk, bqs);
    proj3<<<512, 256, 0, stream>>>(p,  Whq, bqs, Qh, (_Float16*)nullptr, (unsigned short*)nullptr);
    proj3<<<512, 256, 0, stream>>>(bv, Whk, bk,  (_Float16*)nullptr, Ktt, Vb);
    flash_kernel<<<512, 256, 0, stream>>>(Qh, Ktt, Vb, outp);
}